// Round 11
// baseline (547.212 us; speedup 1.0000x reference)
//
#include <hip/hip_runtime.h>
#include <hip/hip_bf16.h>

#define FD 128
#define NPART 8   // one partition per XCD (blockIdx % 8 ~ XCD id on MI355X)

typedef __bf16 bf16x8 __attribute__((ext_vector_type(8)));
typedef float  f32x4  __attribute__((ext_vector_type(4)));
typedef unsigned short u16;
typedef unsigned int   u32;

static __device__ inline u16 f2b(float f) {
    __hip_bfloat16 h = __float2bfloat16(f);   // RNE
    return __builtin_bit_cast(u16, h);
}
static __device__ inline float b2f(u16 u) {
    return __builtin_bit_cast(float, (u32)u << 16);
}
// streaming (non-temporal) load: don't pollute L2 with single-use data
static __device__ inline int ntload_i(const int* p)  { return __builtin_nontemporal_load(p); }
static __device__ inline u16 ntload_u16(const u16* p){ return __builtin_nontemporal_load(p); }

// ---------------- convert x (f32) -> bf16, 8 elems/thread -------------------
__global__ __launch_bounds__(256) void cvt_kernel(
    const float* __restrict__ xp, const float* __restrict__ xa,
    u16* __restrict__ xp16, u16* __restrict__ xa16, int np8, int na8)
{
    int gid = blockIdx.x * 256 + threadIdx.x;    // unit: 8 elements
    const float* src; u16* dst; int idx;
    if (gid < np8)            { src = xp; dst = xp16; idx = gid; }
    else if (gid < np8 + na8) { src = xa; dst = xa16; idx = gid - np8; }
    else return;
    const float4* s4 = (const float4*)(src + (long)idx * 8);
    float4 a = s4[0], b = s4[1];
    u32 o0 = (u32)f2b(a.x) | ((u32)f2b(a.y) << 16);
    u32 o1 = (u32)f2b(a.z) | ((u32)f2b(a.w) << 16);
    u32 o2 = (u32)f2b(b.x) | ((u32)f2b(b.y) << 16);
    u32 o3 = (u32)f2b(b.z) | ((u32)f2b(b.w) << 16);
    ((uint4*)(dst + (long)idx * 8))[0] = make_uint4(o0, o1, o2, o3);
}

// ---------------- weights: combine + convert to bf16 ------------------------
// W16 layout: [Wr_w][Wr_c][Wo_w+Wo_c][Wr_wn][Wo_wn], each 128*128 bf16.
__global__ __launch_bounds__(256) void prep_w_kernel(
    const float* __restrict__ Wr_w, const float* __restrict__ Wr_c,
    const float* __restrict__ Wo_w, const float* __restrict__ Wo_c,
    const float* __restrict__ Wr_wn, const float* __restrict__ Wo_wn,
    const float* __restrict__ br_w, const float* __restrict__ br_c,
    const float* __restrict__ br_wn,
    u16* __restrict__ W16, float* __restrict__ bias_p, float* __restrict__ bias_a)
{
    int i = blockIdx.x * 256 + threadIdx.x;      // 0..16383
    W16[i]             = f2b(Wr_w[i]);
    W16[16384 + i]     = f2b(Wr_c[i]);
    W16[2 * 16384 + i] = f2b(Wo_w[i] + Wo_c[i]);
    W16[3 * 16384 + i] = f2b(Wr_wn[i]);
    W16[4 * 16384 + i] = f2b(Wo_wn[i]);
    if (i < FD) { bias_p[i] = br_w[i] + br_c[i]; bias_a[i] = br_wn[i]; }
}

// ---------------- partitioned degree count (atomics localized per XCD) ------
__global__ __launch_bounds__(256) void count3p_kernel(
    const int* __restrict__ d0, const int* __restrict__ d1, const int* __restrict__ d2,
    int E0, int E1, int E2, int NPn, int nper, int* __restrict__ cnt)
{
    int part = blockIdx.x & (NPART - 1);
    int e = (blockIdx.x >> 3) * 256 + threadIdx.x;
    int di;
    if (e < E0)                di = ntload_i(&d0[e]);
    else if (e < E0 + E1)      di = NPn + ntload_i(&d1[e - E0]);
    else if (e < E0 + E1 + E2) di = 2 * NPn + ntload_i(&d2[e - E0 - E1]);
    else return;
    int lo = part * nper;
    if (di >= lo && di < lo + nper) atomicAdd(&cnt[di], 1);
}

// ---------------- device-wide exclusive scan, 3 phases ----------------------
// Phase A: per-block (1024 elems) sum -> bsum[b]
__global__ __launch_bounds__(256) void scan_a_kernel(
    const int* __restrict__ cnt, int* __restrict__ bsum, int n)
{
    __shared__ int lsum[256];
    int t = threadIdx.x;
    int base = blockIdx.x * 1024 + t * 4;
    int s = 0;
    if (base + 3 < n) {
        int4 v = *(const int4*)(cnt + base);
        s = v.x + v.y + v.z + v.w;
    } else {
        #pragma unroll
        for (int k = 0; k < 4; ++k) if (base + k < n) s += cnt[base + k];
    }
    lsum[t] = s;
    __syncthreads();
    #pragma unroll
    for (int off = 128; off > 0; off >>= 1) {
        if (t < off) lsum[t] += lsum[t + off];
        __syncthreads();
    }
    if (t == 0) bsum[blockIdx.x] = lsum[0];
}

// Phase B: exclusive scan of block sums (nb <= 256); writes offs[n] = total
__global__ __launch_bounds__(256) void scan_b_kernel(
    int* __restrict__ bsum, int* __restrict__ offs, int nb, int n)
{
    __shared__ int lsum[256];
    int t = threadIdx.x;
    int s = (t < nb) ? bsum[t] : 0;
    lsum[t] = s;
    __syncthreads();
    #pragma unroll
    for (int off = 1; off < 256; off <<= 1) {
        int val = (t >= off) ? lsum[t - off] : 0;
        __syncthreads();
        lsum[t] += val;
        __syncthreads();
    }
    if (t < nb) bsum[t] = lsum[t] - s;          // exclusive
    if (t == 255) offs[n] = lsum[255];          // grand total
}

// Phase C: per-block exclusive scan + block offset; writes offs[] and
// overwrites cnt[] in place with the same value (bucket cursor).
__global__ __launch_bounds__(256) void scan_c_kernel(
    int* __restrict__ cnt, const int* __restrict__ bsum,
    int* __restrict__ offs, int n)
{
    __shared__ int lsum[256];
    int t = threadIdx.x;
    int base = blockIdx.x * 1024 + t * 4;
    int4 v = make_int4(0, 0, 0, 0);
    if (base + 3 < n) {
        v = *(const int4*)(cnt + base);
    } else {
        if (base + 0 < n) v.x = cnt[base + 0];
        if (base + 1 < n) v.y = cnt[base + 1];
        if (base + 2 < n) v.z = cnt[base + 2];
        if (base + 3 < n) v.w = cnt[base + 3];
    }
    int s = v.x + v.y + v.z + v.w;
    lsum[t] = s;
    __syncthreads();
    #pragma unroll
    for (int off = 1; off < 256; off <<= 1) {
        int val = (t >= off) ? lsum[t - off] : 0;
        __syncthreads();
        lsum[t] += val;
        __syncthreads();
    }
    int excl = lsum[t] - s + bsum[blockIdx.x];
    int o0 = excl, o1 = o0 + v.x, o2 = o1 + v.y, o3 = o2 + v.z;
    if (base + 3 < n) {
        *(int4*)(offs + base) = make_int4(o0, o1, o2, o3);
        *(int4*)(cnt + base)  = make_int4(o0, o1, o2, o3);
    } else {
        if (base + 0 < n) { offs[base + 0] = o0; cnt[base + 0] = o0; }
        if (base + 1 < n) { offs[base + 1] = o1; cnt[base + 1] = o1; }
        if (base + 2 < n) { offs[base + 2] = o2; cnt[base + 2] = o2; }
        if (base + 3 < n) { offs[base + 3] = o3; cnt[base + 3] = o3; }
    }
}

// ---------------- partitioned bucket: csr writes localized per XCD ----------
// Each block owns dst-partition (blockIdx & 7). Edge-array reads are
// non-temporal so the streaming traffic doesn't evict the write-hot csr
// slice (~0.65 MB) + cursor from that XCD's L2.
__global__ __launch_bounds__(256) void bucket3p_kernel(
    const int* __restrict__ s0, const int* __restrict__ d0,
    const int* __restrict__ s1, const int* __restrict__ d1,
    const int* __restrict__ s2, const int* __restrict__ d2,
    int E0, int E1, int E2, int NPn, int nper,
    int* __restrict__ cursor, u16* __restrict__ csr)
{
    int part = blockIdx.x & (NPART - 1);
    int e = (blockIdx.x >> 3) * 256 + threadIdx.x;
    const int* __restrict__ sp; int di, k;
    if (e < E0)                { k = e;           di = ntload_i(&d0[k]);           sp = s0; }
    else if (e < E0 + E1)      { k = e - E0;      di = NPn + ntload_i(&d1[k]);     sp = s1; }
    else if (e < E0 + E1 + E2) { k = e - E0 - E1; di = 2 * NPn + ntload_i(&d2[k]); sp = s2; }
    else return;
    int lo = part * nper;
    if (di >= lo && di < lo + nper) {
        int sv = ntload_i(&sp[k]);
        int pos = atomicAdd(&cursor[di], 1);
        csr[pos] = (u16)sv;                       // src < 65536 always
    }
}

// ---------------- fused gather-mean (bf16 in/out, f32 accumulate) -----------
// one wave per destination in concat space [wr papers | ci papers | wn authors]
__global__ __launch_bounds__(256) void gather3_kernel(
    const u16* __restrict__ xp16, const u16* __restrict__ xa16,
    const u16* __restrict__ csr, const int* __restrict__ offs,
    u16* __restrict__ mw16, u16* __restrict__ mc16, u16* __restrict__ ma16,
    int NPn, int ntot)
{
    int w = blockIdx.x * 4 + (threadIdx.x >> 6);
    if (w >= ntot) return;
    int lane = threadIdx.x & 63;

    const u16* xs; u16* out;
    if (w < NPn)           { xs = xa16; out = mw16 + (long)w * FD; }
    else if (w < 2 * NPn)  { xs = xp16; out = mc16 + (long)(w - NPn) * FD; }
    else                   { xs = xp16; out = ma16 + (long)(w - 2 * NPn) * FD; }

    int beg = offs[w], end = offs[w + 1];
    float ax = 0.f, ay = 0.f;
    int j = beg;
    for (; j + 3 < end; j += 4) {
        int i0 = ntload_u16(&csr[j]);
        int i1 = ntload_u16(&csr[j + 1]);
        int i2 = ntload_u16(&csr[j + 2]);
        int i3 = ntload_u16(&csr[j + 3]);
        u32 v0 = ((const u32*)(xs + (long)i0 * FD))[lane];
        u32 v1 = ((const u32*)(xs + (long)i1 * FD))[lane];
        u32 v2 = ((const u32*)(xs + (long)i2 * FD))[lane];
        u32 v3 = ((const u32*)(xs + (long)i3 * FD))[lane];
        ax += b2f((u16)v0) + b2f((u16)v1) + b2f((u16)v2) + b2f((u16)v3);
        ay += b2f((u16)(v0 >> 16)) + b2f((u16)(v1 >> 16)) + b2f((u16)(v2 >> 16)) + b2f((u16)(v3 >> 16));
    }
    for (; j < end; ++j) {
        int i0 = ntload_u16(&csr[j]);
        u32 v0 = ((const u32*)(xs + (long)i0 * FD))[lane];
        ax += b2f((u16)v0);
        ay += b2f((u16)(v0 >> 16));
    }
    float ic = (end > beg) ? 1.0f / (float)(end - beg) : 0.0f;
    u32 o = (u32)f2b(ax * ic) | ((u32)f2b(ay * ic) << 16);
    ((u32*)out)[lane] = o;
}

// ---------------- MFMA GEMM: C[n x 128] = sum_p A_p @ W_p^T + bias ----------
// A_p row-major [n,128] bf16; W_p row-major [128,128] bf16; C f32.
// Per wave: 32 rows x 128 cols. No LDS, no barriers. Fragments: contiguous
// bf16x8 per lane (m92-verified layout); C/D: col=lane&15, row=(lane>>4)*4+r.
__global__ __launch_bounds__(256) void gemm_cat_kernel(
    const u16* __restrict__ A0, const u16* __restrict__ A1, const u16* __restrict__ A2,
    const u16* __restrict__ W0, const u16* __restrict__ W1, const u16* __restrict__ W2,
    const float* __restrict__ bias, float* __restrict__ C, int n, int npairs)
{
    int wave = threadIdx.x >> 6, lane = threadIdx.x & 63;
    int m0 = blockIdx.x * 128 + wave * 32;
    if (m0 >= n) return;
    int l16 = lane & 15;
    int khi = (lane >> 4) * 8;           // k sub-offset: 0,8,16,24

    f32x4 acc[2][8] = {};
    const u16* Ap_[3] = {A0, A1, A2};
    const u16* Wp_[3] = {W0, W1, W2};

    for (int p = 0; p < npairs; ++p) {
        const u16* Ap = Ap_[p];
        const u16* Wp = Wp_[p];
        #pragma unroll
        for (int c = 0; c < 4; ++c) {
            int koff = c * 32 + khi;
            bf16x8 af[2];
            #pragma unroll
            for (int mi = 0; mi < 2; ++mi) {
                int row = m0 + mi * 16 + l16;
                row = min(row, n - 1);                  // clamp; store is guarded
                af[mi] = *(const bf16x8*)(Ap + (long)row * FD + koff);
            }
            #pragma unroll
            for (int ni = 0; ni < 8; ++ni) {
                bf16x8 bfr = *(const bf16x8*)(Wp + (ni * 16 + l16) * FD + koff);
                acc[0][ni] = __builtin_amdgcn_mfma_f32_16x16x32_bf16(af[0], bfr, acc[0][ni], 0, 0, 0);
                acc[1][ni] = __builtin_amdgcn_mfma_f32_16x16x32_bf16(af[1], bfr, acc[1][ni], 0, 0, 0);
            }
        }
    }

    int r0 = (lane >> 4) * 4;
    #pragma unroll
    for (int mi = 0; mi < 2; ++mi) {
        #pragma unroll
        for (int ni = 0; ni < 8; ++ni) {
            int col = ni * 16 + l16;
            float b = bias[col];
            #pragma unroll
            for (int r = 0; r < 4; ++r) {
                int row = m0 + mi * 16 + r0 + r;
                if (row < n) C[(long)row * FD + col] = acc[mi][ni][r] + b;
            }
        }
    }
}

extern "C" void kernel_launch(void* const* d_in, const int* in_sizes, int n_in,
                              void* d_out, int out_size, void* d_ws, size_t ws_size,
                              hipStream_t stream) {
    const float* x_paper   = (const float*)d_in[0];
    const float* x_author  = (const float*)d_in[1];
    const int* wr_src      = (const int*)d_in[2];   // author -> paper
    const int* wr_dst      = (const int*)d_in[3];
    const int* wn_src      = (const int*)d_in[4];   // paper -> author
    const int* wn_dst      = (const int*)d_in[5];
    const int* ci_src      = (const int*)d_in[6];   // paper -> paper
    const int* ci_dst      = (const int*)d_in[7];
    const float* Wr_writes  = (const float*)d_in[8];
    const float* br_writes  = (const float*)d_in[9];
    const float* Wo_writes  = (const float*)d_in[10];
    const float* Wr_written = (const float*)d_in[11];
    const float* br_written = (const float*)d_in[12];
    const float* Wo_written = (const float*)d_in[13];
    const float* Wr_cites   = (const float*)d_in[14];
    const float* br_cites   = (const float*)d_in[15];
    const float* Wo_cites   = (const float*)d_in[16];

    const int NP = in_sizes[0] / FD;   // 50000
    const int NA = in_sizes[1] / FD;   // 20000
    const int E_WR = in_sizes[2];      // 800000
    const int E_WN = in_sizes[4];      // 800000
    const int E_CI = in_sizes[6];      // 1000000
    const int E_TOT = E_WR + E_CI + E_WN;
    const int NTOT = 2 * NP + NA;      // concat destination space
    const int NPER = (NTOT + NPART - 1) / NPART;

    float* out_paper  = (float*)d_out;
    float* out_author = out_paper + (long)NP * FD;

    // ---- workspace layout (256B-aligned chunks) ----
    char* wp = (char*)d_ws;
    auto alloc = [&](size_t bytes) { char* p = wp; wp += (bytes + 255) & ~(size_t)255; return p; };
    u16* xp16   = (u16*)alloc((size_t)NP * FD * 2);
    u16* xa16   = (u16*)alloc((size_t)NA * FD * 2);
    u16* mw16   = (u16*)alloc((size_t)NP * FD * 2);
    u16* mc16   = (u16*)alloc((size_t)NP * FD * 2);
    u16* ma16   = (u16*)alloc((size_t)NA * FD * 2);
    u16* W16    = (u16*)alloc(5 * 16384 * 2);
    float* bias_p = (float*)alloc(FD * 4);
    float* bias_a = (float*)alloc(FD * 4);
    u16* csr    = (u16*)alloc((size_t)E_TOT * 2);
    int* offs   = (int*)alloc((size_t)(NTOT + 1) * 4);
    int* cnt    = (int*)alloc((size_t)NTOT * 4);   // counts, then bucket cursor
    int* bsum   = (int*)alloc(256 * 4);

    dim3 blk(256);
    const int SCAN_NB = (NTOT + 1023) / 1024;                 // 118 blocks
    const unsigned EPB = (unsigned)((E_TOT + 255) / 256);     // edge chunks
    dim3 part_grid(EPB * NPART);

    // 1. convert node features to bf16
    int np8 = NP * FD / 8, na8 = NA * FD / 8;
    cvt_kernel<<<dim3((np8 + na8 + 255) / 256), blk, 0, stream>>>(
        x_paper, x_author, xp16, xa16, np8, na8);

    // 2. weights/bias prep
    prep_w_kernel<<<dim3(64), blk, 0, stream>>>(
        Wr_writes, Wr_cites, Wo_writes, Wo_cites, Wr_written, Wo_written,
        br_writes, br_cites, br_written, W16, bias_p, bias_a);

    // 3-6. fused CSR build + gather over all relations
    hipMemsetAsync(cnt, 0, (size_t)NTOT * 4, stream);
    count3p_kernel<<<part_grid, blk, 0, stream>>>(
        wr_dst, ci_dst, wn_dst, E_WR, E_CI, E_WN, NP, NPER, cnt);
    scan_a_kernel<<<dim3(SCAN_NB), blk, 0, stream>>>(cnt, bsum, NTOT);
    scan_b_kernel<<<dim3(1), blk, 0, stream>>>(bsum, offs, SCAN_NB, NTOT);
    scan_c_kernel<<<dim3(SCAN_NB), blk, 0, stream>>>(cnt, bsum, offs, NTOT);
    bucket3p_kernel<<<part_grid, blk, 0, stream>>>(
        wr_src, wr_dst, ci_src, ci_dst, wn_src, wn_dst,
        E_WR, E_CI, E_WN, NP, NPER, cnt, csr);
    gather3_kernel<<<dim3((NTOT + 3) / 4), blk, 0, stream>>>(
        xp16, xa16, csr, offs, mw16, mc16, ma16, NP, NTOT);

    // 7. fused MFMA GEMMs (K-concat)
    gemm_cat_kernel<<<dim3((NP + 127) / 128), blk, 0, stream>>>(
        mw16, mc16, xp16,
        W16, W16 + 16384, W16 + 2 * 16384,
        bias_p, out_paper, NP, 3);
    gemm_cat_kernel<<<dim3((NA + 127) / 128), blk, 0, stream>>>(
        ma16, xa16, xa16,
        W16 + 3 * 16384, W16 + 4 * 16384, W16 + 4 * 16384,
        bias_a, out_author, NA, 2);
}

// Round 15
// 427.751 us; speedup vs baseline: 1.2793x; 1.2793x over previous
//
#include <hip/hip_runtime.h>
#include <hip/hip_bf16.h>

#define FD 128

typedef __bf16 bf16x8 __attribute__((ext_vector_type(8)));
typedef float  f32x4  __attribute__((ext_vector_type(4)));
typedef unsigned short u16;
typedef unsigned int   u32;

static __device__ inline u16 f2b(float f) {
    __hip_bfloat16 h = __float2bfloat16(f);   // RNE
    return __builtin_bit_cast(u16, h);
}
static __device__ inline float b2f(u16 u) {
    return __builtin_bit_cast(float, (u32)u << 16);
}

// ---------------- convert x (f32) -> bf16, 8 elems/thread -------------------
__global__ __launch_bounds__(256) void cvt_kernel(
    const float* __restrict__ xp, const float* __restrict__ xa,
    u16* __restrict__ xp16, u16* __restrict__ xa16, int np8, int na8)
{
    int gid = blockIdx.x * 256 + threadIdx.x;    // unit: 8 elements
    const float* src; u16* dst; int idx;
    if (gid < np8)            { src = xp; dst = xp16; idx = gid; }
    else if (gid < np8 + na8) { src = xa; dst = xa16; idx = gid - np8; }
    else return;
    const float4* s4 = (const float4*)(src + (long)idx * 8);
    float4 a = s4[0], b = s4[1];
    u32 o0 = (u32)f2b(a.x) | ((u32)f2b(a.y) << 16);
    u32 o1 = (u32)f2b(a.z) | ((u32)f2b(a.w) << 16);
    u32 o2 = (u32)f2b(b.x) | ((u32)f2b(b.y) << 16);
    u32 o3 = (u32)f2b(b.z) | ((u32)f2b(b.w) << 16);
    ((uint4*)(dst + (long)idx * 8))[0] = make_uint4(o0, o1, o2, o3);
}

// ---------------- weights: combine + convert to bf16 ------------------------
// W16 layout: [Wr_w][Wr_c][Wo_w+Wo_c][Wr_wn][Wo_wn], each 128*128 bf16.
__global__ __launch_bounds__(256) void prep_w_kernel(
    const float* __restrict__ Wr_w, const float* __restrict__ Wr_c,
    const float* __restrict__ Wo_w, const float* __restrict__ Wo_c,
    const float* __restrict__ Wr_wn, const float* __restrict__ Wo_wn,
    const float* __restrict__ br_w, const float* __restrict__ br_c,
    const float* __restrict__ br_wn,
    u16* __restrict__ W16, float* __restrict__ bias_p, float* __restrict__ bias_a)
{
    int i = blockIdx.x * 256 + threadIdx.x;      // 0..16383
    W16[i]             = f2b(Wr_w[i]);
    W16[16384 + i]     = f2b(Wr_c[i]);
    W16[2 * 16384 + i] = f2b(Wo_w[i] + Wo_c[i]);
    W16[3 * 16384 + i] = f2b(Wr_wn[i]);
    W16[4 * 16384 + i] = f2b(Wo_wn[i]);
    if (i < FD) { bias_p[i] = br_w[i] + br_c[i]; bias_a[i] = br_wn[i]; }
}

// ---------------- count + rank: ONE atomic pass over all edges --------------
// r = atomicAdd(&cnt[d],1) gives this edge's rank within its destination.
// rank[] store is perfectly coalesced (indexed by e).
__global__ __launch_bounds__(256) void count_rank_kernel(
    const int* __restrict__ d0, const int* __restrict__ d1, const int* __restrict__ d2,
    int E0, int E1, int E2, int NPn,
    int* __restrict__ cnt, u16* __restrict__ rank)
{
    int e = blockIdx.x * 256 + threadIdx.x;
    int di;
    if (e < E0)                di = d0[e];
    else if (e < E0 + E1)      di = NPn + d1[e - E0];
    else if (e < E0 + E1 + E2) di = 2 * NPn + d2[e - E0 - E1];
    else return;
    int r = atomicAdd(&cnt[di], 1);
    rank[e] = (u16)r;                  // max degree << 65536
}

// ---------------- device-wide exclusive scan, 3 phases ----------------------
// Phase A: per-block (1024 elems) sum -> bsum[b]
__global__ __launch_bounds__(256) void scan_a_kernel(
    const int* __restrict__ cnt, int* __restrict__ bsum, int n)
{
    __shared__ int lsum[256];
    int t = threadIdx.x;
    int base = blockIdx.x * 1024 + t * 4;
    int s = 0;
    if (base + 3 < n) {
        int4 v = *(const int4*)(cnt + base);
        s = v.x + v.y + v.z + v.w;
    } else {
        #pragma unroll
        for (int k = 0; k < 4; ++k) if (base + k < n) s += cnt[base + k];
    }
    lsum[t] = s;
    __syncthreads();
    #pragma unroll
    for (int off = 128; off > 0; off >>= 1) {
        if (t < off) lsum[t] += lsum[t + off];
        __syncthreads();
    }
    if (t == 0) bsum[blockIdx.x] = lsum[0];
}

// Phase B: exclusive scan of block sums (nb <= 256); writes offs[n] = total
__global__ __launch_bounds__(256) void scan_b_kernel(
    int* __restrict__ bsum, int* __restrict__ offs, int nb, int n)
{
    __shared__ int lsum[256];
    int t = threadIdx.x;
    int s = (t < nb) ? bsum[t] : 0;
    lsum[t] = s;
    __syncthreads();
    #pragma unroll
    for (int off = 1; off < 256; off <<= 1) {
        int val = (t >= off) ? lsum[t - off] : 0;
        __syncthreads();
        lsum[t] += val;
        __syncthreads();
    }
    if (t < nb) bsum[t] = lsum[t] - s;          // exclusive
    if (t == 255) offs[n] = lsum[255];          // grand total
}

// Phase C: per-block exclusive scan + block offset; writes offs[]
__global__ __launch_bounds__(256) void scan_c_kernel(
    const int* __restrict__ cnt, const int* __restrict__ bsum,
    int* __restrict__ offs, int n)
{
    __shared__ int lsum[256];
    int t = threadIdx.x;
    int base = blockIdx.x * 1024 + t * 4;
    int4 v = make_int4(0, 0, 0, 0);
    if (base + 3 < n) {
        v = *(const int4*)(cnt + base);
    } else {
        if (base + 0 < n) v.x = cnt[base + 0];
        if (base + 1 < n) v.y = cnt[base + 1];
        if (base + 2 < n) v.z = cnt[base + 2];
        if (base + 3 < n) v.w = cnt[base + 3];
    }
    int s = v.x + v.y + v.z + v.w;
    lsum[t] = s;
    __syncthreads();
    #pragma unroll
    for (int off = 1; off < 256; off <<= 1) {
        int val = (t >= off) ? lsum[t - off] : 0;
        __syncthreads();
        lsum[t] += val;
        __syncthreads();
    }
    int excl = lsum[t] - s + bsum[blockIdx.x];
    int o0 = excl, o1 = o0 + v.x, o2 = o1 + v.y, o3 = o2 + v.z;
    if (base + 3 < n) {
        *(int4*)(offs + base) = make_int4(o0, o1, o2, o3);
    } else {
        if (base + 0 < n) offs[base + 0] = o0;
        if (base + 1 < n) offs[base + 1] = o1;
        if (base + 2 < n) offs[base + 2] = o2;
        if (base + 3 < n) offs[base + 3] = o3;
    }
}

// ---------------- bucket, ATOMIC-FREE: pos = offs[d] + rank[e] --------------
// Deterministic unique positions; csr stores are ordinary cached writes.
__global__ __launch_bounds__(256) void bucket_rank_kernel(
    const int* __restrict__ s0, const int* __restrict__ d0,
    const int* __restrict__ s1, const int* __restrict__ d1,
    const int* __restrict__ s2, const int* __restrict__ d2,
    int E0, int E1, int E2, int NPn,
    const int* __restrict__ offs, const u16* __restrict__ rank,
    u16* __restrict__ csr)
{
    int e = blockIdx.x * 256 + threadIdx.x;
    int di, sv;
    if (e < E0)                { di = d0[e];                 sv = s0[e]; }
    else if (e < E0 + E1)      { int k = e - E0;      di = NPn + d1[k];     sv = s1[k]; }
    else if (e < E0 + E1 + E2) { int k = e - E0 - E1; di = 2 * NPn + d2[k]; sv = s2[k]; }
    else return;
    int pos = offs[di] + (int)rank[e];
    csr[pos] = (u16)sv;                          // src < 65536 always
}

// ---------------- fused gather-mean (bf16 in/out, f32 accumulate) -----------
// one wave per destination in concat space [wr papers | ci papers | wn authors]
__global__ __launch_bounds__(256) void gather3_kernel(
    const u16* __restrict__ xp16, const u16* __restrict__ xa16,
    const u16* __restrict__ csr, const int* __restrict__ offs,
    u16* __restrict__ mw16, u16* __restrict__ mc16, u16* __restrict__ ma16,
    int NPn, int ntot)
{
    int w = blockIdx.x * 4 + (threadIdx.x >> 6);
    if (w >= ntot) return;
    int lane = threadIdx.x & 63;

    const u16* xs; u16* out;
    if (w < NPn)           { xs = xa16; out = mw16 + (long)w * FD; }
    else if (w < 2 * NPn)  { xs = xp16; out = mc16 + (long)(w - NPn) * FD; }
    else                   { xs = xp16; out = ma16 + (long)(w - 2 * NPn) * FD; }

    int beg = offs[w], end = offs[w + 1];
    float ax = 0.f, ay = 0.f;
    int j = beg;
    for (; j + 3 < end; j += 4) {
        int i0 = csr[j], i1 = csr[j + 1], i2 = csr[j + 2], i3 = csr[j + 3];
        u32 v0 = ((const u32*)(xs + (long)i0 * FD))[lane];
        u32 v1 = ((const u32*)(xs + (long)i1 * FD))[lane];
        u32 v2 = ((const u32*)(xs + (long)i2 * FD))[lane];
        u32 v3 = ((const u32*)(xs + (long)i3 * FD))[lane];
        ax += b2f((u16)v0) + b2f((u16)v1) + b2f((u16)v2) + b2f((u16)v3);
        ay += b2f((u16)(v0 >> 16)) + b2f((u16)(v1 >> 16)) + b2f((u16)(v2 >> 16)) + b2f((u16)(v3 >> 16));
    }
    for (; j < end; ++j) {
        int i0 = csr[j];
        u32 v0 = ((const u32*)(xs + (long)i0 * FD))[lane];
        ax += b2f((u16)v0);
        ay += b2f((u16)(v0 >> 16));
    }
    float ic = (end > beg) ? 1.0f / (float)(end - beg) : 0.0f;
    u32 o = (u32)f2b(ax * ic) | ((u32)f2b(ay * ic) << 16);
    ((u32*)out)[lane] = o;
}

// ---------------- MFMA GEMM: C[n x 128] = sum_p A_p @ W_p^T + bias ----------
// A_p row-major [n,128] bf16; W_p row-major [128,128] bf16; C f32.
// Per wave: 32 rows x 128 cols. No LDS, no barriers. Fragments: contiguous
// bf16x8 per lane (m92-verified layout); C/D: col=lane&15, row=(lane>>4)*4+r.
__global__ __launch_bounds__(256) void gemm_cat_kernel(
    const u16* __restrict__ A0, const u16* __restrict__ A1, const u16* __restrict__ A2,
    const u16* __restrict__ W0, const u16* __restrict__ W1, const u16* __restrict__ W2,
    const float* __restrict__ bias, float* __restrict__ C, int n, int npairs)
{
    int wave = threadIdx.x >> 6, lane = threadIdx.x & 63;
    int m0 = blockIdx.x * 128 + wave * 32;
    if (m0 >= n) return;
    int l16 = lane & 15;
    int khi = (lane >> 4) * 8;           // k sub-offset: 0,8,16,24

    f32x4 acc[2][8] = {};
    const u16* Ap_[3] = {A0, A1, A2};
    const u16* Wp_[3] = {W0, W1, W2};

    for (int p = 0; p < npairs; ++p) {
        const u16* Ap = Ap_[p];
        const u16* Wp = Wp_[p];
        #pragma unroll
        for (int c = 0; c < 4; ++c) {
            int koff = c * 32 + khi;
            bf16x8 af[2];
            #pragma unroll
            for (int mi = 0; mi < 2; ++mi) {
                int row = m0 + mi * 16 + l16;
                row = min(row, n - 1);                  // clamp; store is guarded
                af[mi] = *(const bf16x8*)(Ap + (long)row * FD + koff);
            }
            #pragma unroll
            for (int ni = 0; ni < 8; ++ni) {
                bf16x8 bfr = *(const bf16x8*)(Wp + (ni * 16 + l16) * FD + koff);
                acc[0][ni] = __builtin_amdgcn_mfma_f32_16x16x32_bf16(af[0], bfr, acc[0][ni], 0, 0, 0);
                acc[1][ni] = __builtin_amdgcn_mfma_f32_16x16x32_bf16(af[1], bfr, acc[1][ni], 0, 0, 0);
            }
        }
    }

    int r0 = (lane >> 4) * 4;
    #pragma unroll
    for (int mi = 0; mi < 2; ++mi) {
        #pragma unroll
        for (int ni = 0; ni < 8; ++ni) {
            int col = ni * 16 + l16;
            float b = bias[col];
            #pragma unroll
            for (int r = 0; r < 4; ++r) {
                int row = m0 + mi * 16 + r0 + r;
                if (row < n) C[(long)row * FD + col] = acc[mi][ni][r] + b;
            }
        }
    }
}

extern "C" void kernel_launch(void* const* d_in, const int* in_sizes, int n_in,
                              void* d_out, int out_size, void* d_ws, size_t ws_size,
                              hipStream_t stream) {
    const float* x_paper   = (const float*)d_in[0];
    const float* x_author  = (const float*)d_in[1];
    const int* wr_src      = (const int*)d_in[2];   // author -> paper
    const int* wr_dst      = (const int*)d_in[3];
    const int* wn_src      = (const int*)d_in[4];   // paper -> author
    const int* wn_dst      = (const int*)d_in[5];
    const int* ci_src      = (const int*)d_in[6];   // paper -> paper
    const int* ci_dst      = (const int*)d_in[7];
    const float* Wr_writes  = (const float*)d_in[8];
    const float* br_writes  = (const float*)d_in[9];
    const float* Wo_writes  = (const float*)d_in[10];
    const float* Wr_written = (const float*)d_in[11];
    const float* br_written = (const float*)d_in[12];
    const float* Wo_written = (const float*)d_in[13];
    const float* Wr_cites   = (const float*)d_in[14];
    const float* br_cites   = (const float*)d_in[15];
    const float* Wo_cites   = (const float*)d_in[16];

    const int NP = in_sizes[0] / FD;   // 50000
    const int NA = in_sizes[1] / FD;   // 20000
    const int E_WR = in_sizes[2];      // 800000
    const int E_WN = in_sizes[4];      // 800000
    const int E_CI = in_sizes[6];      // 1000000
    const int E_TOT = E_WR + E_CI + E_WN;
    const int NTOT = 2 * NP + NA;      // concat destination space

    float* out_paper  = (float*)d_out;
    float* out_author = out_paper + (long)NP * FD;

    // ---- workspace layout (256B-aligned chunks) ----
    char* wp = (char*)d_ws;
    auto alloc = [&](size_t bytes) { char* p = wp; wp += (bytes + 255) & ~(size_t)255; return p; };
    u16* xp16   = (u16*)alloc((size_t)NP * FD * 2);
    u16* xa16   = (u16*)alloc((size_t)NA * FD * 2);
    u16* mw16   = (u16*)alloc((size_t)NP * FD * 2);
    u16* mc16   = (u16*)alloc((size_t)NP * FD * 2);
    u16* ma16   = (u16*)alloc((size_t)NA * FD * 2);
    u16* W16    = (u16*)alloc(5 * 16384 * 2);
    float* bias_p = (float*)alloc(FD * 4);
    float* bias_a = (float*)alloc(FD * 4);
    u16* csr    = (u16*)alloc((size_t)E_TOT * 2);
    u16* rank   = (u16*)alloc((size_t)E_TOT * 2);
    int* offs   = (int*)alloc((size_t)(NTOT + 1) * 4);
    int* cnt    = (int*)alloc((size_t)NTOT * 4);
    int* bsum   = (int*)alloc(256 * 4);

    dim3 blk(256);
    const int SCAN_NB = (NTOT + 1023) / 1024;                 // 118 blocks
    dim3 egrid((unsigned)((E_TOT + 255) / 256));

    // 1. convert node features to bf16
    int np8 = NP * FD / 8, na8 = NA * FD / 8;
    cvt_kernel<<<dim3((np8 + na8 + 255) / 256), blk, 0, stream>>>(
        x_paper, x_author, xp16, xa16, np8, na8);

    // 2. weights/bias prep
    prep_w_kernel<<<dim3(64), blk, 0, stream>>>(
        Wr_writes, Wr_cites, Wo_writes, Wo_cites, Wr_written, Wo_written,
        br_writes, br_cites, br_written, W16, bias_p, bias_a);

    // 3-6. CSR build (one atomic pass + scan + atomic-free scatter) + gather
    hipMemsetAsync(cnt, 0, (size_t)NTOT * 4, stream);
    count_rank_kernel<<<egrid, blk, 0, stream>>>(
        wr_dst, ci_dst, wn_dst, E_WR, E_CI, E_WN, NP, cnt, rank);
    scan_a_kernel<<<dim3(SCAN_NB), blk, 0, stream>>>(cnt, bsum, NTOT);
    scan_b_kernel<<<dim3(1), blk, 0, stream>>>(bsum, offs, SCAN_NB, NTOT);
    scan_c_kernel<<<dim3(SCAN_NB), blk, 0, stream>>>(cnt, bsum, offs, NTOT);
    bucket_rank_kernel<<<egrid, blk, 0, stream>>>(
        wr_src, wr_dst, ci_src, ci_dst, wn_src, wn_dst,
        E_WR, E_CI, E_WN, NP, offs, rank, csr);
    gather3_kernel<<<dim3((NTOT + 3) / 4), blk, 0, stream>>>(
        xp16, xa16, csr, offs, mw16, mc16, ma16, NP, NTOT);

    // 7. fused MFMA GEMMs (K-concat)
    gemm_cat_kernel<<<dim3((NP + 127) / 128), blk, 0, stream>>>(
        mw16, mc16, xp16,
        W16, W16 + 16384, W16 + 2 * 16384,
        bias_p, out_paper, NP, 3);
    gemm_cat_kernel<<<dim3((NA + 127) / 128), blk, 0, stream>>>(
        ma16, xa16, xa16,
        W16 + 3 * 16384, W16 + 4 * 16384, W16 + 4 * 16384,
        bias_a, out_author, NA, 2);
}